// Round 10
// baseline (16780.569 us; speedup 1.0000x reference)
//
#include <hip/hip_runtime.h>
#include <math.h>

#define BATCH 2048
#define STEPS 512
#define EMB   128
#define HID   256
#define INGRU 641          // EMB + STEPS + 1

// ws layout (R5-proven, total 688,896 floats = 2,755,584 B = exactly
// sizeof(W_ih)+sizeof(W_hh); fits the workspace as measured in R4/R5/R7):
//   float4 Whp[64 k4][256 d][3 g] : Whp[..] = W_hh[g*256+d][4k4..4k4+3]
//   float4 Wxp[32 k4][256 d][3 g] : Wxp[..] = W_ih[g*256+d][4k4..4k4+3]
//   float  Wcol[513 c][768 gg]    : Wcol[c][gg] = W_ih[gg][EMB+c]
#define WXP_OFF  49152                      // float4 index (64*768)
#define WCOL_OFF 294912                     // float index

__global__ void prep_weights(const float* __restrict__ W_ih,
                             const float* __restrict__ W_hh,
                             float* __restrict__ ws) {
    const int idx = blockIdx.x * 256 + threadIdx.x;     // < 513*768
    float4* __restrict__ Wp = (float4*)ws;
    if (idx < 49152) {                 // Whp
        const int k4 = idx / 768, rem = idx % 768;
        const int d = rem / 3, g = rem % 3;
        Wp[idx] = *(const float4*)(W_hh + ((size_t)(g * 256 + d)) * HID + 4 * k4);
    }
    if (idx < 24576) {                 // Wxp (unaligned source rows)
        const int k4 = idx / 768, rem = idx % 768;
        const int d = rem / 3, g = rem % 3;
        const float* src = W_ih + ((size_t)(g * 256 + d)) * INGRU + 4 * k4;
        Wp[WXP_OFF + idx] = make_float4(src[0], src[1], src[2], src[3]);
    }
    if (idx < 513 * 768) {             // Wcol
        const int c = idx / 768, gg = idx % 768;
        ws[WCOL_OFF + (size_t)c * 768 + gg] = W_ih[(size_t)gg * INGRU + EMB + c];
    }
}

// ---- helpers (R5 verbatim; k-ascending chains preserved) ----
#define FMA8(ACC, S, A, B) do {                                           \
    ACC[0] = fmaf(S, (A).x, ACC[0]); ACC[1] = fmaf(S, (A).y, ACC[1]);     \
    ACC[2] = fmaf(S, (A).z, ACC[2]); ACC[3] = fmaf(S, (A).w, ACC[3]);     \
    ACC[4] = fmaf(S, (B).x, ACC[4]); ACC[5] = fmaf(S, (B).y, ACC[5]);     \
    ACC[6] = fmaf(S, (B).z, ACC[6]); ACC[7] = fmaf(S, (B).w, ACC[7]);     \
} while (0)

#define K1(A0, A1, A2, S0, S1, S2, HP, OFF) do {                          \
    const float4 hA = *(const float4*)((HP) + (OFF));                     \
    const float4 hB = *(const float4*)((HP) + (OFF) + 4);                 \
    FMA8(A0, S0, hA, hB); FMA8(A1, S1, hA, hB); FMA8(A2, S2, hA, hB);     \
} while (0)

#define CONS(A0, A1, A2, W0, W1, W2, HP) do {                             \
    K1(A0, A1, A2, (W0).x, (W1).x, (W2).x, HP, 0);                        \
    K1(A0, A1, A2, (W0).y, (W1).y, (W2).y, HP, 12);                       \
    K1(A0, A1, A2, (W0).z, (W1).z, (W2).z, HP, 24);                       \
    K1(A0, A1, A2, (W0).w, (W1).w, (W2).w, HP, 36);                       \
} while (0)

__device__ __forceinline__ float f4e(const float4 v, int e) {
    return e == 0 ? v.x : e == 1 ? v.y : e == 2 ? v.z : v.w;
}

// one k4 of the x-GEMM from 8 row-float4s (X direct, wave-uniform loads)
#define XCONS(W0, W1, W2, XQ) do {                                        \
    _Pragma("unroll")                                                     \
    for (int e = 0; e < 4; ++e) {                                         \
        const float w0e = f4e(W0, e), w1e = f4e(W1, e), w2e = f4e(W2, e); \
        _Pragma("unroll")                                                 \
        for (int j = 0; j < 8; ++j) {                                     \
            const float xv = f4e(XQ[j], e);                               \
            aI0[j] = fmaf(w0e, xv, aI0[j]);                               \
            aI1[j] = fmaf(w1e, xv, aI1[j]);                               \
            aI2[j] = fmaf(w2e, xv, aI2[j]);                               \
        }                                                                 \
    }                                                                     \
} while (0)

// One WG = 8 batch rows, persistent over 512 steps. 512 threads:
//   waves 0-3 (t<256, d=t)    : x-GEMM (K=128, X DIRECT from global —
//     read-only, L1-safe) + Wcol tag gather + gates + classifier + h write
//   waves 4-7 (t>=256, d=t&255): h-GEMM (K=256, h from LDS broadcast —
//     R5-proven coherent transport)
// All fma chains, seeds, classifier tree, epilogue bit-identical to R1.
__global__ __launch_bounds__(512, 2) void gru_policy(
    const float* __restrict__ X,      // [B][STEPS][EMB]
    const float* __restrict__ ws,
    const float* __restrict__ b_ih,   // [768]
    const float* __restrict__ b_hh,   // [768]
    const float* __restrict__ W_cf,   // [2][256]
    const float* __restrict__ b_cf,   // [2]
    float* __restrict__ out)          // [B*STEPS] actions | [B*STEPS] pis
{
    const float4* __restrict__ Wp   = (const float4*)ws;
    const float*  __restrict__ Wcol = ws + WCOL_OFF;

    __shared__ __align__(16) float h_lds[2][HID][12];   // 24.6 KB
    __shared__ float ah_lds[3][8][256];                 // 24.6 KB
    __shared__ __align__(16) float red[8][8];           // [j][wv*2+c]

    const int t     = threadIdx.x;
    const int xduty = (t < 256);
    const int d     = t & 255;
    const int wv    = t >> 6;        // x-waves: 0..3
    const int lane  = t & 63;
    const size_t r0 = (size_t)blockIdx.x * 8;
    const size_t xstride = (size_t)STEPS * EMB;

    const float bh0 = b_hh[d], bh1 = b_hh[d + 256], bh2 = b_hh[d + 512];
    const float bi0 = b_ih[d], bi1 = b_ih[d + 256], bi2 = b_ih[d + 512];
    const float wcf0 = W_cf[d], wcf1 = W_cf[256 + d];
    const float bc0 = b_cf[0], bc1 = b_cf[1];

    int   tags[8];
    float hp[8];
    #pragma unroll
    for (int j = 0; j < 8; ++j) { tags[j] = 0; hp[j] = 0.0f; }

    // X row base pointers (wave-uniform)
    const float* xb[8];
    #pragma unroll
    for (int j = 0; j < 8; ++j) xb[j] = X + (r0 + j) * xstride;

    // init: zero h_lds[0]
    for (int i = t; i < HID * 8; i += 512) h_lds[0][i >> 3][i & 7] = 0.0f;
    __syncthreads();

    int cur = 0;
    for (int s = 0; s < STEPS; ++s) {
        float aI0[8], aI1[8], aI2[8];
        if (!xduty) {
            // ======== h-duty: K=256 from LDS broadcast (R5 verbatim) ========
            float aH0[8], aH1[8], aH2[8];
            #pragma unroll
            for (int j = 0; j < 8; ++j) { aH0[j] = bh0; aH1[j] = bh1; aH2[j] = bh2; }

            const float* hb = &h_lds[cur][0][0];
            const float4* wp = Wp + (size_t)d * 3;
            float4 a0 = wp[0], a1 = wp[1], a2 = wp[2]; wp += 768;
            float4 b0 = wp[0], b1 = wp[1], b2 = wp[2]; wp += 768;

            __builtin_amdgcn_s_setprio(1);
            #pragma unroll 2
            for (int it = 0; it < 62; it += 2) {
                const float4 c0 = wp[0], c1 = wp[1], c2 = wp[2]; wp += 768;
                const float4 e0 = wp[0], e1 = wp[1], e2 = wp[2]; wp += 768;
                CONS(aH0, aH1, aH2, a0, a1, a2, hb + it * 48);
                CONS(aH0, aH1, aH2, b0, b1, b2, hb + it * 48 + 48);
                a0 = c0; a1 = c1; a2 = c2; b0 = e0; b1 = e1; b2 = e2;
            }
            CONS(aH0, aH1, aH2, a0, a1, a2, hb + 62 * 48);
            CONS(aH0, aH1, aH2, b0, b1, b2, hb + 63 * 48);
            __builtin_amdgcn_s_setprio(0);

            #pragma unroll
            for (int j = 0; j < 8; ++j) {
                ah_lds[0][j][d] = aH0[j];
                ah_lds[1][j][d] = aH1[j];
                ah_lds[2][j][d] = aH2[j];
            }
        } else {
            // ==== x-duty: Wcol tag gather + x-GEMM (K=128, X direct) ====
            #pragma unroll
            for (int j = 0; j < 8; ++j) {
                const size_t tg = (size_t)tags[j] * 768;
                aI0[j] = bi0 + Wcol[tg + d];
                aI1[j] = bi1 + Wcol[tg + 256 + d];
                aI2[j] = bi2 + Wcol[tg + 512 + d];
            }
            const size_t so = (size_t)s * EMB;
            const float4* wq = Wp + WXP_OFF + (size_t)d * 3;
            #pragma unroll 4
            for (int k4 = 0; k4 < 32; ++k4) {
                const float4 w0 = wq[0], w1 = wq[1], w2 = wq[2]; wq += 768;
                float4 xq[8];
                #pragma unroll
                for (int j = 0; j < 8; ++j)
                    xq[j] = *(const float4*)(xb[j] + so + 4 * k4);
                XCONS(w0, w1, w2, xq);
            }
        }
        __syncthreads();   // B1: ah_lds ready; h_lds[cur] reads done

        if (xduty) {
            // ---- gates, h_new, classifier (R1 formulas & tree) ----
            float p0[8], p1[8], hn[8];
            #pragma unroll
            for (int j = 0; j < 8; ++j) {
                const float ah0 = ah_lds[0][j][d];
                const float ah1 = ah_lds[1][j][d];
                const float ah2 = ah_lds[2][j][d];
                const float rr = 1.0f / (1.0f + expf(-(aI0[j] + ah0)));
                const float zz = 1.0f / (1.0f + expf(-(aI1[j] + ah1)));
                const float nn = tanhf(aI2[j] + rr * ah2);
                const float h  = (1.0f - zz) * nn + zz * hp[j];
                hp[j] = h;
                hn[j] = h;
                p0[j] = h * wcf0;
                p1[j] = h * wcf1;
            }
            *(float4*)(&h_lds[cur ^ 1][d][0]) =
                make_float4(hn[0], hn[1], hn[2], hn[3]);
            *(float4*)(&h_lds[cur ^ 1][d][4]) =
                make_float4(hn[4], hn[5], hn[6], hn[7]);

            #pragma unroll
            for (int m = 32; m >= 1; m >>= 1) {
                #pragma unroll
                for (int j = 0; j < 8; ++j) {
                    p0[j] += __shfl_xor(p0[j], m, 64);
                    p1[j] += __shfl_xor(p1[j], m, 64);
                }
            }
            if (lane == 0) {
                #pragma unroll
                for (int j = 0; j < 8; ++j) {
                    red[j][wv * 2]     = p0[j];
                    red[j][wv * 2 + 1] = p1[j];
                }
            }
        }
        __syncthreads();   // B2: h_lds[nxt], red visible

        if (xduty) {
            // every x-thread tracks all 8 tags locally (no 3rd barrier)
            #pragma unroll
            for (int j = 0; j < 8; ++j) {
                const float4 rA = *(const float4*)&red[j][0];
                const float4 rB = *(const float4*)&red[j][4];
                float l0 = bc0; l0 += rA.x; l0 += rA.z; l0 += rB.x; l0 += rB.z;
                float l1 = bc1; l1 += rA.y; l1 += rA.w; l1 += rB.y; l1 += rB.w;
                const int act = (l1 > l0) ? 1 : 0;
                tags[j] += act;
                if (t == j) {
                    const float mx = fmaxf(l0, l1);
                    const float e0 = expf(l0 - mx), e1 = expf(l1 - mx);
                    const float pi = (act ? e1 : e0) / (e0 + e1);
                    const size_t row = r0 + j;
                    out[row * STEPS + s] = (float)act;
                    out[(size_t)BATCH * STEPS + row * STEPS + s] = pi;
                }
            }
        }
        cur ^= 1;
    }
}

extern "C" void kernel_launch(void* const* d_in, const int* in_sizes, int n_in,
                              void* d_out, int out_size, void* d_ws, size_t ws_size,
                              hipStream_t stream) {
    const float* X    = (const float*)d_in[0];
    const float* W_ih = (const float*)d_in[1];
    const float* W_hh = (const float*)d_in[2];
    const float* b_ih = (const float*)d_in[3];
    const float* b_hh = (const float*)d_in[4];
    const float* W_cf = (const float*)d_in[5];
    const float* b_cf = (const float*)d_in[6];
    float* out = (float*)d_out;
    float* ws  = (float*)d_ws;

    prep_weights<<<1539, 256, 0, stream>>>(W_ih, W_hh, ws);
    gru_policy<<<BATCH / 8, 512, 0, stream>>>(X, ws, b_ih, b_hh, W_cf, b_cf, out);
}

// Round 13
// 9756.924 us; speedup vs baseline: 1.7199x; 1.7199x over previous
//
#include <hip/hip_runtime.h>
#include <math.h>

#define BATCH 2048
#define STEPS 512
#define EMB   128
#define HID   256
#define INGRU 641          // EMB + STEPS + 1

// ws layout (R5-proven, total 688,896 floats = exactly the two weight mats):
//   float4 Whp[64 k4][256 d][3 g] : Whp[..] = W_hh[g*256+d][4k4..4k4+3]
//   float4 Wxp[32 k4][256 d][3 g] : Wxp[..] = W_ih[g*256+d][4k4..4k4+3]
//   float  Wcol[513 c][768 gg]    : Wcol[c][gg] = W_ih[gg][EMB+c]
#define WXP_OFF  49152                      // float4 index (64*768)
#define WCOL_OFF 294912                     // float index

__global__ void prep_weights(const float* __restrict__ W_ih,
                             const float* __restrict__ W_hh,
                             float* __restrict__ ws) {
    const int idx = blockIdx.x * 256 + threadIdx.x;     // < 513*768
    float4* __restrict__ Wp = (float4*)ws;
    if (idx < 49152) {                 // Whp
        const int k4 = idx / 768, rem = idx % 768;
        const int d = rem / 3, g = rem % 3;
        Wp[idx] = *(const float4*)(W_hh + ((size_t)(g * 256 + d)) * HID + 4 * k4);
    }
    if (idx < 24576) {                 // Wxp (unaligned source rows)
        const int k4 = idx / 768, rem = idx % 768;
        const int d = rem / 3, g = rem % 3;
        const float* src = W_ih + ((size_t)(g * 256 + d)) * INGRU + 4 * k4;
        Wp[WXP_OFF + idx] = make_float4(src[0], src[1], src[2], src[3]);
    }
    if (idx < 513 * 768) {             // Wcol
        const int c = idx / 768, gg = idx % 768;
        ws[WCOL_OFF + (size_t)c * 768 + gg] = W_ih[(size_t)gg * INGRU + EMB + c];
    }
}

// ---- R5 helpers (k-ascending chains preserved) ----
#define FMA8(ACC, S, A, B) do {                                           \
    ACC[0] = fmaf(S, (A).x, ACC[0]); ACC[1] = fmaf(S, (A).y, ACC[1]);     \
    ACC[2] = fmaf(S, (A).z, ACC[2]); ACC[3] = fmaf(S, (A).w, ACC[3]);     \
    ACC[4] = fmaf(S, (B).x, ACC[4]); ACC[5] = fmaf(S, (B).y, ACC[5]);     \
    ACC[6] = fmaf(S, (B).z, ACC[6]); ACC[7] = fmaf(S, (B).w, ACC[7]);     \
} while (0)

#define K1(A0, A1, A2, S0, S1, S2, HP, OFF) do {                          \
    const float4 hA = *(const float4*)((HP) + (OFF));                     \
    const float4 hB = *(const float4*)((HP) + (OFF) + 4);                 \
    FMA8(A0, S0, hA, hB); FMA8(A1, S1, hA, hB); FMA8(A2, S2, hA, hB);     \
} while (0)

#define CONS(A0, A1, A2, W0, W1, W2, HP) do {                             \
    K1(A0, A1, A2, (W0).x, (W1).x, (W2).x, HP, 0);                        \
    K1(A0, A1, A2, (W0).y, (W1).y, (W2).y, HP, 12);                       \
    K1(A0, A1, A2, (W0).z, (W1).z, (W2).z, HP, 24);                       \
    K1(A0, A1, A2, (W0).w, (W1).w, (W2).w, HP, 36);                       \
} while (0)

// 4-deep ring: consume slot Q (oldest in flight), immediately prefetch the
// k4 four ahead into the same slot. All wb indices are literals (rule #20).
#define SLOT4(A0, A1, A2, Q) do {                                         \
    const float4 u0 = wb[Q][0], u1 = wb[Q][1], u2 = wb[Q][2];             \
    wb[Q][0] = wp[0]; wb[Q][1] = wp[1]; wb[Q][2] = wp[2]; wp += 768;      \
    CONS(A0, A1, A2, u0, u1, u2, hb); hb += 48;                           \
} while (0)

#define SLOTE(A0, A1, A2, Q) do {                                         \
    CONS(A0, A1, A2, wb[Q][0], wb[Q][1], wb[Q][2], hb); hb += 48;         \
} while (0)

// One WG = 8 batch rows, persistent over 512 steps. 512 threads:
//   waves 0-3 (t<256, d=t)    : h-GEMM (K=256) + gates + classifier
//   waves 4-7 (t>=256, d=t&255): x-GEMM (K=128) + tag gather + x staging
// Identical to the R5 kernel (9.24 ms, proven deterministic) except the
// weight streams are 4-deep software-pipelined instead of 2-deep.
__global__ __launch_bounds__(512, 2) void gru_policy(
    const float* __restrict__ X,      // [B][STEPS][EMB]
    const float* __restrict__ ws,
    const float* __restrict__ b_ih,   // [768]
    const float* __restrict__ b_hh,   // [768]
    const float* __restrict__ W_cf,   // [2][256]
    const float* __restrict__ b_cf,   // [2]
    float* __restrict__ out)          // [B*STEPS] actions | [B*STEPS] pis
{
    const float4* __restrict__ Wp   = (const float4*)ws;
    const float*  __restrict__ Wcol = ws + WCOL_OFF;

    __shared__ __align__(16) float h_lds[2][HID][12];   // 24.6 KB
    __shared__ __align__(16) float x_lds[EMB][12];      //  6.1 KB
    __shared__ float ai_lds[3][8][256];                 // 24.6 KB
    __shared__ float red[4][8][2];
    __shared__ int   tag_lds[8];

    const int t    = threadIdx.x;
    const int d    = t & 255;
    const int half = t >> 8;          // 0 = h-duty, 1 = x-duty
    const int wv   = t >> 6;
    const int lane = t & 63;
    const size_t r0 = (size_t)blockIdx.x * 8;
    const size_t xstride = (size_t)STEPS * EMB;

    const float bc0 = b_cf[0], bc1 = b_cf[1];
    float bh0 = 0.f, bh1 = 0.f, bh2 = 0.f, wcf0 = 0.f, wcf1 = 0.f;
    float bi0 = 0.f, bi1 = 0.f, bi2 = 0.f;
    if (half == 0) {
        bh0 = b_hh[d]; bh1 = b_hh[d + 256]; bh2 = b_hh[d + 512];
        wcf0 = W_cf[d]; wcf1 = W_cf[HID + d];
    } else {
        bi0 = b_ih[d]; bi1 = b_ih[d + 256]; bi2 = b_ih[d + 512];
    }

    // init: h=0 (h-waves), x step0 (x-waves), tags
    if (half == 0) {
        const float4 z4 = make_float4(0.f, 0.f, 0.f, 0.f);
        *(float4*)(&h_lds[0][d][0]) = z4;
        *(float4*)(&h_lds[0][d][4]) = z4;
    } else {
        #pragma unroll
        for (int q = 0; q < 4; ++q) {
            const int i = d + 256 * q, row = i >> 7, col = i & 127;
            x_lds[col][row] = X[(r0 + row) * xstride + col];
        }
    }
    if (t < 8) tag_lds[t] = 0;
    __syncthreads();

    int cur = 0;
    for (int s = 0; s < STEPS; ++s) {
        float aH0[8], aH1[8], aH2[8];
        float xv[4];
        if (half == 0) {
            // ---- h-GEMM: K=256, k ascending, 4-deep weight ring ----
            #pragma unroll
            for (int j = 0; j < 8; ++j) { aH0[j] = bh0; aH1[j] = bh1; aH2[j] = bh2; }
            const float* hb = &h_lds[cur][0][0];
            const float4* wp = Wp + (size_t)d * 3;
            float4 wb[4][3];
            #pragma unroll
            for (int q = 0; q < 4; ++q) {
                wb[q][0] = wp[0]; wb[q][1] = wp[1]; wb[q][2] = wp[2]; wp += 768;
            }
            __builtin_amdgcn_s_setprio(1);
            #pragma unroll 1
            for (int it = 0; it < 15; ++it) {    // consume k4=4it..4it+3
                SLOT4(aH0, aH1, aH2, 0);
                SLOT4(aH0, aH1, aH2, 1);
                SLOT4(aH0, aH1, aH2, 2);
                SLOT4(aH0, aH1, aH2, 3);
            }
            SLOTE(aH0, aH1, aH2, 0);             // k4 = 60..63
            SLOTE(aH0, aH1, aH2, 1);
            SLOTE(aH0, aH1, aH2, 2);
            SLOTE(aH0, aH1, aH2, 3);
            __builtin_amdgcn_s_setprio(0);
        } else {
            // ---- x-duty: tag gather + next-x loads + K=128 GEMM ----
            float aI0[8], aI1[8], aI2[8];
            #pragma unroll
            for (int j = 0; j < 8; ++j) {
                const size_t tg = (size_t)tag_lds[j] * 768;
                aI0[j] = bi0 + Wcol[tg + d];
                aI1[j] = bi1 + Wcol[tg + 256 + d];
                aI2[j] = bi2 + Wcol[tg + 512 + d];
            }
            if (s + 1 < STEPS) {
                #pragma unroll
                for (int q = 0; q < 4; ++q) {
                    const int i = d + 256 * q, row = i >> 7, col = i & 127;
                    xv[q] = X[(r0 + row) * xstride + (size_t)(s + 1) * EMB + col];
                }
            }
            const float* hb = &x_lds[0][0];
            const float4* wp = Wp + WXP_OFF + (size_t)d * 3;
            float4 wb[4][3];
            #pragma unroll
            for (int q = 0; q < 4; ++q) {
                wb[q][0] = wp[0]; wb[q][1] = wp[1]; wb[q][2] = wp[2]; wp += 768;
            }
            #pragma unroll 1
            for (int it = 0; it < 7; ++it) {     // consume k4=4it..4it+3
                SLOT4(aI0, aI1, aI2, 0);
                SLOT4(aI0, aI1, aI2, 1);
                SLOT4(aI0, aI1, aI2, 2);
                SLOT4(aI0, aI1, aI2, 3);
            }
            SLOTE(aI0, aI1, aI2, 0);             // k4 = 28..31
            SLOTE(aI0, aI1, aI2, 1);
            SLOTE(aI0, aI1, aI2, 2);
            SLOTE(aI0, aI1, aI2, 3);
            // publish aI (conflict-free: consecutive d per (g,j))
            #pragma unroll
            for (int j = 0; j < 8; ++j) {
                ai_lds[0][j][d] = aI0[j];
                ai_lds[1][j][d] = aI1[j];
                ai_lds[2][j][d] = aI2[j];
            }
        }
        __syncthreads();   // B1: aI ready; h/x LDS reads done

        if (half == 0) {
            // ---- gates, h_new, classifier (R1 formulas & tree) ----
            const float4 hpA = *(const float4*)(&h_lds[cur][d][0]);
            const float4 hpB = *(const float4*)(&h_lds[cur][d][4]);
            const float hpj[8] = {hpA.x, hpA.y, hpA.z, hpA.w,
                                  hpB.x, hpB.y, hpB.z, hpB.w};
            float hn[8], p0[8], p1[8];
            #pragma unroll
            for (int j = 0; j < 8; ++j) {
                const float i0 = ai_lds[0][j][d];
                const float i1 = ai_lds[1][j][d];
                const float i2 = ai_lds[2][j][d];
                const float rr = 1.0f / (1.0f + expf(-(i0 + aH0[j])));
                const float zz = 1.0f / (1.0f + expf(-(i1 + aH1[j])));
                const float nn = tanhf(i2 + rr * aH2[j]);
                const float h  = (1.0f - zz) * nn + zz * hpj[j];
                hn[j] = h;
                p0[j] = h * wcf0;
                p1[j] = h * wcf1;
            }
            *(float4*)(&h_lds[cur ^ 1][d][0]) =
                make_float4(hn[0], hn[1], hn[2], hn[3]);
            *(float4*)(&h_lds[cur ^ 1][d][4]) =
                make_float4(hn[4], hn[5], hn[6], hn[7]);
            #pragma unroll
            for (int m = 32; m >= 1; m >>= 1) {
                #pragma unroll
                for (int j = 0; j < 8; ++j) {
                    p0[j] += __shfl_xor(p0[j], m, 64);
                    p1[j] += __shfl_xor(p1[j], m, 64);
                }
            }
            if (lane == 0) {
                #pragma unroll
                for (int j = 0; j < 8; ++j) {
                    red[wv][j][0] = p0[j];
                    red[wv][j][1] = p1[j];
                }
            }
        } else {
            // stage next x (old-x reads finished before B1)
            if (s + 1 < STEPS) {
                #pragma unroll
                for (int q = 0; q < 4; ++q) {
                    const int i = d + 256 * q, row = i >> 7, col = i & 127;
                    x_lds[col][row] = xv[q];
                }
            }
        }
        __syncthreads();   // B2: h_new, red, x staged

        // ---- softmax / argmax / tag, one thread per row ----
        if (t < 8) {
            float l0 = bc0, l1 = bc1;
            #pragma unroll
            for (int w = 0; w < 4; ++w) {     // ascending dim blocks, as R1
                l0 += red[w][t][0];
                l1 += red[w][t][1];
            }
            const int act = (l1 > l0) ? 1 : 0;
            const float mx = fmaxf(l0, l1);
            const float e0 = expf(l0 - mx), e1 = expf(l1 - mx);
            const float pi = (act ? e1 : e0) / (e0 + e1);
            const size_t row = r0 + t;
            out[row * STEPS + s] = (float)act;
            out[(size_t)BATCH * STEPS + row * STEPS + s] = pi;
            tag_lds[t] += act;
        }
        __syncthreads();   // B3: tags ready for next gather
        cur ^= 1;
    }
}

extern "C" void kernel_launch(void* const* d_in, const int* in_sizes, int n_in,
                              void* d_out, int out_size, void* d_ws, size_t ws_size,
                              hipStream_t stream) {
    const float* X    = (const float*)d_in[0];
    const float* W_ih = (const float*)d_in[1];
    const float* W_hh = (const float*)d_in[2];
    const float* b_ih = (const float*)d_in[3];
    const float* b_hh = (const float*)d_in[4];
    const float* W_cf = (const float*)d_in[5];
    const float* b_cf = (const float*)d_in[6];
    float* out = (float*)d_out;
    float* ws  = (float*)d_ws;

    prep_weights<<<1539, 256, 0, stream>>>(W_ih, W_hh, ws);
    gru_policy<<<BATCH / 8, 512, 0, stream>>>(X, ws, b_ih, b_hh, W_cf, b_cf, out);
}